// Round 12
// baseline (1666.948 us; speedup 1.0000x reference)
//
#include <hip/hip_runtime.h>

typedef _Float16 f16x8 __attribute__((ext_vector_type(8)));
typedef float f32x16 __attribute__((ext_vector_type(16)));

#define V_TOTAL 8192
#define C_DIM   64
#define N_TOK   32768
#define THR_COEF 2.2e-3f

#define VSPLIT1 4
#define VSEG1   2048
#define CH1     32
#define BCAP    60          // per-token bucket capacity (in d_out scratch)
#define OCAP    131000      // overflow list capacity

typedef const __attribute__((address_space(1))) _Float16 glb_f16;
typedef __attribute__((address_space(3))) _Float16 lds_f16;

// ws float offsets:
//   cp      f16[524288]  @ 0        hi-only packed codes: granule cv(32 codes):
//                                   cv*2048 + q*256 + c*8  (f16 units, k=q*8+j)
//   keys    u64[32768]   @ 262144
//   cnt     u32[32768]   @ 327680
//   ovfc    u32          @ 360448
//   counts  int[8192]    @ 360512
//   blocksq f32[256]     @ 368704
//   fin_cnt int          @ 368960
// d_out scratch (overwritten by finalize):
//   buck  u32[32768*60] @ 0 ; ovf u32[] @ 1966080 (cap OCAP)

__device__ __forceinline__ unsigned long long packkey(float s, int idx) {
    unsigned u = __float_as_uint(s);
    unsigned k = u ^ ((unsigned)(((int)u) >> 31) | 0x80000000u);
    return ((unsigned long long)k << 32) | (unsigned)(8191 - idx);
}

__global__ __launch_bounds__(256)
void k_prep(const float* __restrict__ w, _Float16* __restrict__ cp,
            unsigned long long* __restrict__ keys, unsigned* __restrict__ cnt,
            unsigned* __restrict__ ovfc, int* __restrict__ counts,
            int* __restrict__ fin_cnt) {
    int v = blockIdx.x * 256 + threadIdx.x;   // one code per thread
    counts[v] = 0;
#pragma unroll
    for (int i = 0; i < 4; ++i) { keys[v * 4 + i] = 0ull; cnt[v * 4 + i] = 0u; }
    if (v == 0) { ovfc[0] = 0u; fin_cnt[0] = 0; }
    const float4* row = (const float4*)(w + v * C_DIM);
    float4 r[16];
    float s = 0.f;
#pragma unroll
    for (int i = 0; i < 16; ++i) {
        r[i] = row[i];
        s += r[i].x * r[i].x + r[i].y * r[i].y + r[i].z * r[i].z + r[i].w * r[i].w;
    }
    float inv = 1.0f / fmaxf(sqrtf(s), 1e-12f);
    const float* rs = (const float*)r;
    const int cv = v >> 5, c = v & 31;
#pragma unroll
    for (int q = 0; q < 8; ++q) {
        f16x8 hi;
#pragma unroll
        for (int j = 0; j < 8; ++j) hi[j] = (_Float16)(rs[q * 8 + j] * inv);
        *(f16x8*)(cp + cv * 2048 + q * 256 + c * 8) = hi;
    }
}

// Scan: hi-only MFMA; running-threshold candidate append (no top-2, no classify).
__global__ __launch_bounds__(256, 4)
void k_scan(const float* __restrict__ f, const _Float16* __restrict__ cp,
            unsigned* __restrict__ cnt, unsigned* __restrict__ buck,
            unsigned* __restrict__ ovf, unsigned* __restrict__ ovfc) {
    __shared__ __align__(16) _Float16 lds[4][4096];

    const int tid  = threadIdx.x;
    const int lane = tid & 63;
    const int wid  = tid >> 6;
    const int c31  = lane & 31;
    const int g    = lane >> 5;
    const int seg  = blockIdx.y;
    const int t0   = blockIdx.x * 128 + wid * 32;
    const int T    = t0 + c31;          // this lane's token

    f16x8 bh[4];
    float s2 = 0.f;
    {
        const float* fb = f + (T >> 10) * 65536 + (T & 1023);
#pragma unroll
        for (int ks = 0; ks < 4; ++ks) {
#pragma unroll
            for (int j = 0; j < 8; ++j) {
                float v = fb[(ks * 16 + g * 8 + j) * 1024];
                s2 += v * v;
                bh[ks][j] = (_Float16)v;
            }
        }
    }
    s2 += __shfl_xor(s2, 32);                       // full ||f||^2
    const float thr = THR_COEF * sqrtf(s2);         // = 2*eps certificate bound

    const _Float16* seg_cp = cp + (size_t)seg * 131072;   // 64 granules * 2048

    auto stage = [&](int cv) {
        const _Float16* src = seg_cp + cv * 4096 + wid * 1024 + lane * 8;
        _Float16* d0 = &lds[cv & 3][wid * 1024];
        __builtin_amdgcn_global_load_lds((glb_f16*)src,         (lds_f16*)d0,         16, 0, 0);
        __builtin_amdgcn_global_load_lds((glb_f16*)(src + 512), (lds_f16*)(d0 + 512), 16, 0, 0);
    };

    const f32x16 zacc = {0.f,0.f,0.f,0.f,0.f,0.f,0.f,0.f,0.f,0.f,0.f,0.f,0.f,0.f,0.f,0.f};

    float mm = -3.4e38f;           // running (max sim_hi) - thr
    const int code_off = 4 * g;

    stage(0); stage(1); stage(2);

#pragma unroll 1
    for (int cv = 0; cv < CH1; ++cv) {
        if (cv < CH1 - 2)       asm volatile("s_waitcnt vmcnt(4)" ::: "memory");
        else if (cv == CH1 - 2) asm volatile("s_waitcnt vmcnt(2)" ::: "memory");
        else                    asm volatile("s_waitcnt vmcnt(0)" ::: "memory");
        __builtin_amdgcn_s_barrier();
        if (cv + 3 < CH1) stage(cv + 3);

        const _Float16* base = &lds[cv & 3][g * 256 + c31 * 8];
#pragma unroll
        for (int tile = 0; tile < 2; ++tile) {
            const _Float16* tb = base + tile * 2048;
            f16x8 A0 = *(const f16x8*)(tb);
            f16x8 A1 = *(const f16x8*)(tb + 512);
            f16x8 A2 = *(const f16x8*)(tb + 1024);
            f16x8 A3 = *(const f16x8*)(tb + 1536);
            f32x16 acc;
            acc = __builtin_amdgcn_mfma_f32_32x32x16_f16(A0, bh[0], zacc, 0, 0, 0);
            acc = __builtin_amdgcn_mfma_f32_32x32x16_f16(A1, bh[1], acc, 0, 0, 0);
            acc = __builtin_amdgcn_mfma_f32_32x32x16_f16(A2, bh[2], acc, 0, 0, 0);
            acc = __builtin_amdgcn_mfma_f32_32x32x16_f16(A3, bh[3], acc, 0, 0, 0);

            const int cb = seg * VSEG1 + cv * 64 + tile * 32 + code_off;
#pragma unroll
            for (int r = 0; r < 16; ++r) {
                const float s = acc[r];
                const bool cand = (s >= mm);          // pre-update filter
                mm = fmaxf(mm, s - thr);
                if (cand) {
                    const int code = cb + (r & 3) + 8 * (r >> 2);
                    unsigned pos = atomicAdd(&cnt[T], 1u);
                    if (pos < BCAP) {
                        buck[T * BCAP + pos] = (unsigned)code;
                    } else {
                        unsigned op = atomicAdd(ovfc, 1u);
                        if (op < OCAP) ovf[op] = ((unsigned)T << 13) | (unsigned)code;
                    }
                }
            }
        }
    }
}

// One wave per token: exact f32 rescore of its candidates, wave-argmax.
__global__ __launch_bounds__(64)
void k_dots(const float* __restrict__ f, const float* __restrict__ w,
            const unsigned* __restrict__ cnt, const unsigned* __restrict__ buck,
            unsigned long long* __restrict__ keys) {
    __shared__ float sf[64];
    const int t    = blockIdx.x;
    const int lane = threadIdx.x;

    const int bb = t >> 10;
    const int hw = t & 1023;
    sf[lane] = f[bb * 65536 + lane * 1024 + hw];
    __syncthreads();

    const int nc = min((int)cnt[t], BCAP);
    float bs = -3.4e38f;
    int   bc = 0x7FFFFFFF;

    for (int k = lane; k < nc; k += 64) {
        const int c = (int)buck[t * BCAP + k];
        const float4* wr = (const float4*)(w + c * C_DIM);
        float d = 0.f, ss = 0.f;
#pragma unroll
        for (int i = 0; i < 16; ++i) {
            float4 wv = wr[i];
            d  = fmaf(sf[i*4+0], wv.x, d);  ss = fmaf(wv.x, wv.x, ss);
            d  = fmaf(sf[i*4+1], wv.y, d);  ss = fmaf(wv.y, wv.y, ss);
            d  = fmaf(sf[i*4+2], wv.z, d);  ss = fmaf(wv.z, wv.z, ss);
            d  = fmaf(sf[i*4+3], wv.w, d);  ss = fmaf(wv.w, wv.w, ss);
        }
        const float s = d / fmaxf(sqrtf(ss), 1e-12f);
        if (s > bs || (s == bs && c < bc)) { bs = s; bc = c; }
    }
#pragma unroll
    for (int off = 32; off > 0; off >>= 1) {
        float os = __shfl_xor(bs, off);
        int   oc = __shfl_xor(bc, off);
        if (os > bs || (os == bs && oc < bc)) { bs = os; bc = oc; }
    }
    if (lane == 0) atomicMax(&keys[t], packkey(bs, bc));
}

// Overflow entries: lane-per-entry exact rescore.
__global__ __launch_bounds__(64)
void k_ovf(const float* __restrict__ f, const float* __restrict__ w,
           const unsigned* __restrict__ ovf, const unsigned* __restrict__ ovfc,
           unsigned long long* __restrict__ keys) {
    const int n = min((int)ovfc[0], OCAP);
    for (int i = blockIdx.x * 64 + threadIdx.x; i < n; i += gridDim.x * 64) {
        const unsigned e = ovf[i];
        const int t = (int)(e >> 13);
        const int c = (int)(e & 8191u);
        const int bb = t >> 10;
        const int hw = t & 1023;
        const float* fb = f + bb * 65536 + hw;
        const float4* wr = (const float4*)(w + c * C_DIM);
        float d = 0.f, ss = 0.f;
#pragma unroll
        for (int i4 = 0; i4 < 16; ++i4) {
            float4 wv = wr[i4];
            d  = fmaf(fb[(i4*4+0)*1024], wv.x, d);  ss = fmaf(wv.x, wv.x, ss);
            d  = fmaf(fb[(i4*4+1)*1024], wv.y, d);  ss = fmaf(wv.y, wv.y, ss);
            d  = fmaf(fb[(i4*4+2)*1024], wv.z, d);  ss = fmaf(wv.z, wv.z, ss);
            d  = fmaf(fb[(i4*4+3)*1024], wv.w, d);  ss = fmaf(wv.w, wv.w, ss);
        }
        const float s = d / fmaxf(sqrtf(ss), 1e-12f);
        atomicMax(&keys[t], packkey(s, c));
    }
}

// finalize (+fused stats via last-block ticket)
__global__ __launch_bounds__(128)
void k_finalize(const float* __restrict__ f, const float* __restrict__ w,
                const unsigned long long* __restrict__ keys,
                int* __restrict__ counts, float* __restrict__ blocksq,
                int* __restrict__ fin_cnt, float* __restrict__ out) {
    __shared__ float red[128];
    __shared__ int sflag;
    const int tid = threadIdx.x;
    const int t   = blockIdx.x * 128 + tid;

    const int bi = 8191 - (int)(unsigned)(keys[t] & 0xFFFFFFFFull);
    atomicAdd(&counts[bi], 1);

    float4 cr[16];
    const float4* crow = (const float4*)(w + bi * C_DIM);
#pragma unroll
    for (int i = 0; i < 16; ++i) cr[i] = crow[i];
    const float* crs = (const float*)cr;

    const int bb = t >> 10;
    const int hw = t & 1023;
    const float* fb = f + bb * 65536 + hw;
    float*       ob = out + bb * 65536 + hw;

    float s = 0.f;
#pragma unroll
    for (int c = 0; c < C_DIM; ++c) {
        float fv = fb[c * 1024];
        float d  = crs[c] - fv;
        s += d * d;
        ob[c * 1024] = fv + d;   // f + sg(fhat - f)
    }

    red[tid] = s;
    __syncthreads();
    for (int st = 64; st > 0; st >>= 1) {
        if (tid < st) red[tid] += red[tid + st];
        __syncthreads();
    }
    if (tid == 0) blocksq[blockIdx.x] = red[0];

    if (tid == 0) {
        __threadfence();
        int old = atomicAdd(fin_cnt, 1);
        sflag = (old == (int)gridDim.x - 1) ? 1 : 0;
    }
    __syncthreads();
    if (sflag) {
        __threadfence();
        __shared__ float redf[128];
        __shared__ int   redi[128];
        int used = 0;
        for (int v = tid; v < V_TOTAL; v += 128) used += (counts[v] > 0) ? 1 : 0;
        redi[tid] = used;
        redf[tid] = blocksq[tid] + blocksq[tid + 128];
        __syncthreads();
        for (int st = 64; st > 0; st >>= 1) {
            if (tid < st) { redi[tid] += redi[tid + st]; redf[tid] += redf[tid + st]; }
            __syncthreads();
        }
        if (tid == 0) {
            float mse = redf[0] / 2097152.0f;
            out[2097152] = 0.25f * mse + mse;
            out[2097153] = 0.0f;
            out[2097154] = 100.0f * (float)redi[0] / 8192.0f;
        }
    }
}

extern "C" void kernel_launch(void* const* d_in, const int* in_sizes, int n_in,
                              void* d_out, int out_size, void* d_ws, size_t ws_size,
                              hipStream_t stream) {
    const float* f = (const float*)d_in[0];
    const float* w = (const float*)d_in[1];
    float* out = (float*)d_out;
    float* ws  = (float*)d_ws;

    _Float16*           cp      = (_Float16*)ws;
    unsigned long long* keys    = (unsigned long long*)(ws + 262144);
    unsigned*           cnt     = (unsigned*)(ws + 327680);
    unsigned*           ovfc    = (unsigned*)(ws + 360448);
    int*                counts  = (int*)(ws + 360512);
    float*              blocksq = ws + 368704;
    int*                fin_cnt = (int*)(ws + 368960);

    unsigned* buck = (unsigned*)out;                 // 32768*60 = 1,966,080
    unsigned* ovf  = ((unsigned*)out) + 1966080;     // cap OCAP

    hipLaunchKernelGGL(k_prep, dim3(32), dim3(256), 0, stream,
                       w, cp, keys, cnt, ovfc, counts, fin_cnt);
    hipLaunchKernelGGL(k_scan, dim3(N_TOK / 128, VSPLIT1), dim3(256), 0, stream,
                       f, cp, cnt, buck, ovf, ovfc);
    hipLaunchKernelGGL(k_dots, dim3(N_TOK), dim3(64), 0, stream,
                       f, w, cnt, buck, keys);
    hipLaunchKernelGGL(k_ovf, dim3(256), dim3(64), 0, stream,
                       f, w, ovf, ovfc, keys);
    hipLaunchKernelGGL(k_finalize, dim3(N_TOK / 128), dim3(128), 0, stream,
                       f, w, keys, counts, blocksq, fin_cnt, out);
}

// Round 13
// 225.283 us; speedup vs baseline: 7.3993x; 7.3993x over previous
//
#include <hip/hip_runtime.h>

typedef _Float16 f16x8 __attribute__((ext_vector_type(8)));
typedef float f32x16 __attribute__((ext_vector_type(16)));

#define V_TOTAL 8192
#define C_DIM   64
#define N_TOK   32768
#define THR_COEF 2.2e-3f
#define VSPLIT  4
#define CH1     32          // 64-code chunks per seg (4 segs x 32 x 64 = 8192)
#define BCAP    16

typedef const __attribute__((address_space(1))) _Float16 glb_f16;
typedef __attribute__((address_space(3))) _Float16 lds_f16;

// ws float offsets:
//   cp      f16[524288] @ 0        hi-only packed codes, granule cv (32 codes):
//                                  cv*2048 + q*256 + c*8   (k = q*8+j)
//   winv    f32[8192]   @ 262144   1/||w_row||
//   fn2     f32[32768]  @ 270336
//   bcnt    u32[32768]  @ 303104
//   bucket  u8[32768*16]@ 335872   (131072 floats)
//   idxf    int[32768]  @ 466944
//   counts  int[8192]   @ 499712
//   blocksq f32[256]    @ 507904
//   fin_cnt int         @ 508160
// d_out scratch (fully overwritten by finalize):
//   tm f32[64][32768] @ 0          per-(128-code tile, token) hi-sim max

__global__ __launch_bounds__(256)
void k_prep(const float* __restrict__ w, _Float16* __restrict__ cp,
            float* __restrict__ winv, int* __restrict__ counts,
            int* __restrict__ fin_cnt) {
    int v = blockIdx.x * 256 + threadIdx.x;   // one code per thread
    counts[v] = 0;
    if (v == 0) fin_cnt[0] = 0;
    const float4* row = (const float4*)(w + v * C_DIM);
    float4 r[16];
    float s = 0.f;
#pragma unroll
    for (int i = 0; i < 16; ++i) {
        r[i] = row[i];
        s += r[i].x * r[i].x + r[i].y * r[i].y + r[i].z * r[i].z + r[i].w * r[i].w;
    }
    float inv = 1.0f / fmaxf(sqrtf(s), 1e-12f);
    winv[v] = inv;
    const float* rs = (const float*)r;
    const int cv = v >> 5, c = v & 31;
#pragma unroll
    for (int q = 0; q < 8; ++q) {
        f16x8 hi;
#pragma unroll
        for (int j = 0; j < 8; ++j) hi[j] = (_Float16)(rs[q * 8 + j] * inv);
        *(f16x8*)(cp + cv * 2048 + q * 256 + c * 8) = hi;
    }
}

// Scan: hi-only MFMA; epilogue = per-128-code-tile max only (no index tracking).
__global__ __launch_bounds__(256, 4)
void k_scan(const float* __restrict__ f, const _Float16* __restrict__ cp,
            float* __restrict__ tm, float* __restrict__ fn2) {
    __shared__ __align__(16) _Float16 lds[4][4096];

    const int tid  = threadIdx.x;
    const int lane = tid & 63;
    const int wid  = tid >> 6;
    const int c31  = lane & 31;
    const int g    = lane >> 5;
    const int seg  = blockIdx.y;
    const int t0   = blockIdx.x * 128 + wid * 32;

    f16x8 bh[4];
    float s2 = 0.f;
    {
        const int T = t0 + c31;
        const float* fb = f + (T >> 10) * 65536 + (T & 1023);
#pragma unroll
        for (int ks = 0; ks < 4; ++ks) {
#pragma unroll
            for (int j = 0; j < 8; ++j) {
                float v = fb[(ks * 16 + g * 8 + j) * 1024];
                s2 += v * v;
                bh[ks][j] = (_Float16)v;
            }
        }
    }
    s2 += __shfl_xor(s2, 32);
    if (lane < 32 && seg == 0) fn2[t0 + c31] = s2;

    const _Float16* seg_cp = cp + (size_t)seg * 131072;   // 64 granules * 2048

    auto stage = [&](int cv) {
        const _Float16* src = seg_cp + cv * 4096 + wid * 1024 + lane * 8;
        _Float16* d0 = &lds[cv & 3][wid * 1024];
        __builtin_amdgcn_global_load_lds((glb_f16*)src,         (lds_f16*)d0,         16, 0, 0);
        __builtin_amdgcn_global_load_lds((glb_f16*)(src + 512), (lds_f16*)(d0 + 512), 16, 0, 0);
    };

    const f32x16 zacc = {0.f,0.f,0.f,0.f,0.f,0.f,0.f,0.f,0.f,0.f,0.f,0.f,0.f,0.f,0.f,0.f};

    float pm = -3.4e38f;   // even-chunk max, pending pair-combine

    stage(0); stage(1); stage(2);

#pragma unroll 1
    for (int cv = 0; cv < CH1; ++cv) {
        if (cv < CH1 - 2)       asm volatile("s_waitcnt vmcnt(4)" ::: "memory");
        else if (cv == CH1 - 2) asm volatile("s_waitcnt vmcnt(2)" ::: "memory");
        else                    asm volatile("s_waitcnt vmcnt(0)" ::: "memory");
        __builtin_amdgcn_s_barrier();
        if (cv + 3 < CH1) stage(cv + 3);

        const _Float16* base = &lds[cv & 3][g * 256 + c31 * 8];
        float tmax[2];
#pragma unroll
        for (int tile = 0; tile < 2; ++tile) {
            const _Float16* tb = base + tile * 2048;
            f16x8 A0 = *(const f16x8*)(tb);
            f16x8 A1 = *(const f16x8*)(tb + 512);
            f16x8 A2 = *(const f16x8*)(tb + 1024);
            f16x8 A3 = *(const f16x8*)(tb + 1536);
            f32x16 acc;
            acc = __builtin_amdgcn_mfma_f32_32x32x16_f16(A0, bh[0], zacc, 0, 0, 0);
            acc = __builtin_amdgcn_mfma_f32_32x32x16_f16(A1, bh[1], acc, 0, 0, 0);
            acc = __builtin_amdgcn_mfma_f32_32x32x16_f16(A2, bh[2], acc, 0, 0, 0);
            acc = __builtin_amdgcn_mfma_f32_32x32x16_f16(A3, bh[3], acc, 0, 0, 0);

            float x0 = fmaxf(fmaxf(acc[0],  acc[1]),  acc[2]);
            float x1 = fmaxf(fmaxf(acc[3],  acc[4]),  acc[5]);
            float x2 = fmaxf(fmaxf(acc[6],  acc[7]),  acc[8]);
            float x3 = fmaxf(fmaxf(acc[9],  acc[10]), acc[11]);
            float x4 = fmaxf(fmaxf(acc[12], acc[13]), acc[14]);
            float y0 = fmaxf(fmaxf(x0, x1), x2);
            float y1 = fmaxf(fmaxf(x3, x4), acc[15]);
            tmax[tile] = fmaxf(y0, y1);
        }
        float cm = fmaxf(tmax[0], tmax[1]);
        cm = fmaxf(cm, __shfl_xor(cm, 32));
        if (cv & 1) {
            if (lane < 32)
                tm[(((seg << 4) | (cv >> 1)) << 15) + t0 + c31] = fmaxf(pm, cm);
        } else {
            pm = cm;
        }
    }
}

// Select: per token m1 over 64 tile-maxes, X = m1 - thr, emit surviving tiles
// into a fixed 16-slot bucket (no atomics). >16 survivors => rescan-all marker.
__global__ __launch_bounds__(256)
void k_select(const float* __restrict__ tm, const float* __restrict__ fn2,
              unsigned* __restrict__ bcnt, unsigned char* __restrict__ bucket) {
    __shared__ float stm[64][128];    // 32 KB
    __shared__ float red[2][128];
    __shared__ float Xs[128];
    const int tid = threadIdx.x;
    const int b   = blockIdx.x;       // token stripe [b*128, b*128+128)

    for (int k = tid; k < 8192; k += 256) {
        const int j  = k >> 7;
        const int tt = k & 127;
        stm[j][tt] = tm[(j << 15) + b * 128 + tt];
    }
    __syncthreads();

    const int tt = tid & 127;
    const int h  = tid >> 7;
    float m = -3.4e38f;
#pragma unroll
    for (int jj = 0; jj < 32; ++jj) m = fmaxf(m, stm[h * 32 + jj][tt]);
    red[h][tt] = m;
    __syncthreads();
    if (h == 0) {
        const float m1 = fmaxf(red[0][tt], red[1][tt]);
        Xs[tt] = m1 - THR_COEF * sqrtf(fn2[b * 128 + tt]);
    }
    __syncthreads();
    if (h == 0) {
        const float X = Xs[tt];
        const int t = b * 128 + tt;
        unsigned char* bk = bucket + t * BCAP;
        int n = 0;
        for (int j = 0; j < 64; ++j) {
            if (stm[j][tt] >= X) {
                if (n < BCAP) bk[n] = (unsigned char)j;
                ++n;
            }
        }
        bcnt[t] = (unsigned)n;
    }
}

// Rescore: one wave per token; exact f32 dots over bucketed 128-code tiles.
__global__ __launch_bounds__(256)
void k_rescore(const float* __restrict__ f, const float* __restrict__ w,
               const float* __restrict__ winv, const unsigned* __restrict__ bcnt,
               const unsigned char* __restrict__ bucket, int* __restrict__ idxf) {
    __shared__ float sf[4][64];
    const int tid  = threadIdx.x;
    const int wid  = tid >> 6;
    const int lane = tid & 63;
    const int wave = blockIdx.x * 4 + wid;

    for (int t = wave; t < N_TOK; t += gridDim.x * 4) {
        const int bb = t >> 10;
        const int hw = t & 1023;
        sf[wid][lane] = f[bb * 65536 + lane * 1024 + hw];
        asm volatile("s_waitcnt lgkmcnt(0)" ::: "memory");
        __builtin_amdgcn_sched_barrier(0);
        const float* sp = &sf[wid][0];

        float bs = -3.4e38f;
        int   bc = 0x7FFFFFFF;

        auto score = [&](int c) {
            const float4* wr = (const float4*)(w + c * C_DIM);
            float d = 0.f;
#pragma unroll
            for (int i = 0; i < 16; ++i) {
                float4 wv = wr[i];
                d = fmaf(sp[4 * i + 0], wv.x, d);
                d = fmaf(sp[4 * i + 1], wv.y, d);
                d = fmaf(sp[4 * i + 2], wv.z, d);
                d = fmaf(sp[4 * i + 3], wv.w, d);
            }
            const float s = d * winv[c];
            if (s > bs || (s == bs && c < bc)) { bs = s; bc = c; }
        };

        const int n = (int)bcnt[t];
        if (n <= BCAP) {
            for (int i = 0; i < n; ++i) {
                const int j  = (int)bucket[t * BCAP + i];
                const int cb = ((j >> 4) << 11) | ((j & 15) << 7);
                score(cb + lane);
                score(cb + 64 + lane);
            }
        } else {
            for (int j = 0; j < 64; ++j) {
                const int cb = ((j >> 4) << 11) | ((j & 15) << 7);
                score(cb + lane);
                score(cb + 64 + lane);
            }
        }

#pragma unroll
        for (int off = 32; off > 0; off >>= 1) {
            float os = __shfl_xor(bs, off);
            int   oc = __shfl_xor(bc, off);
            if (os > bs || (os == bs && oc < bc)) { bs = os; bc = oc; }
        }
        if (lane == 0) idxf[t] = bc;
    }
}

// finalize (+fused stats via last-block ticket)
__global__ __launch_bounds__(128)
void k_finalize(const float* __restrict__ f, const float* __restrict__ w,
                const int* __restrict__ idxf,
                int* __restrict__ counts, float* __restrict__ blocksq,
                int* __restrict__ fin_cnt, float* __restrict__ out) {
    __shared__ float red[128];
    __shared__ int sflag;
    const int tid = threadIdx.x;
    const int t   = blockIdx.x * 128 + tid;

    const int bi = idxf[t];
    atomicAdd(&counts[bi], 1);

    float4 cr[16];
    const float4* crow = (const float4*)(w + bi * C_DIM);
#pragma unroll
    for (int i = 0; i < 16; ++i) cr[i] = crow[i];
    const float* crs = (const float*)cr;

    const int bb = t >> 10;
    const int hw = t & 1023;
    const float* fb = f + bb * 65536 + hw;
    float*       ob = out + bb * 65536 + hw;

    float s = 0.f;
#pragma unroll
    for (int c = 0; c < C_DIM; ++c) {
        float fv = fb[c * 1024];
        float d  = crs[c] - fv;
        s += d * d;
        ob[c * 1024] = fv + d;   // f + sg(fhat - f)
    }

    red[tid] = s;
    __syncthreads();
    for (int st = 64; st > 0; st >>= 1) {
        if (tid < st) red[tid] += red[tid + st];
        __syncthreads();
    }
    if (tid == 0) blocksq[blockIdx.x] = red[0];

    if (tid == 0) {
        __threadfence();
        int old = atomicAdd(fin_cnt, 1);
        sflag = (old == (int)gridDim.x - 1) ? 1 : 0;
    }
    __syncthreads();
    if (sflag) {
        __threadfence();
        __shared__ float redf[128];
        __shared__ int   redi[128];
        int used = 0;
        for (int v = tid; v < V_TOTAL; v += 128) used += (counts[v] > 0) ? 1 : 0;
        redi[tid] = used;
        redf[tid] = blocksq[tid] + blocksq[tid + 128];
        __syncthreads();
        for (int st = 64; st > 0; st >>= 1) {
            if (tid < st) { redi[tid] += redi[tid + st]; redf[tid] += redf[tid + st]; }
            __syncthreads();
        }
        if (tid == 0) {
            float mse = redf[0] / 2097152.0f;
            out[2097152] = 0.25f * mse + mse;
            out[2097153] = 0.0f;
            out[2097154] = 100.0f * (float)redi[0] / 8192.0f;
        }
    }
}

extern "C" void kernel_launch(void* const* d_in, const int* in_sizes, int n_in,
                              void* d_out, int out_size, void* d_ws, size_t ws_size,
                              hipStream_t stream) {
    const float* f = (const float*)d_in[0];
    const float* w = (const float*)d_in[1];
    float* out = (float*)d_out;
    float* ws  = (float*)d_ws;

    _Float16*      cp      = (_Float16*)ws;
    float*         winv    = ws + 262144;
    float*         fn2     = ws + 270336;
    unsigned*      bcnt    = (unsigned*)(ws + 303104);
    unsigned char* bucket  = (unsigned char*)(ws + 335872);
    int*           idxf    = (int*)(ws + 466944);
    int*           counts  = (int*)(ws + 499712);
    float*         blocksq = ws + 507904;
    int*           fin_cnt = (int*)(ws + 508160);

    float* tm = out;   // d_out scratch, overwritten by finalize

    hipLaunchKernelGGL(k_prep, dim3(32), dim3(256), 0, stream,
                       w, cp, winv, counts, fin_cnt);
    hipLaunchKernelGGL(k_scan, dim3(N_TOK / 128, VSPLIT), dim3(256), 0, stream,
                       f, cp, tm, fn2);
    hipLaunchKernelGGL(k_select, dim3(N_TOK / 128), dim3(256), 0, stream,
                       tm, fn2, bcnt, bucket);
    hipLaunchKernelGGL(k_rescore, dim3(512), dim3(256), 0, stream,
                       f, w, winv, bcnt, bucket, idxf);
    hipLaunchKernelGGL(k_finalize, dim3(N_TOK / 128), dim3(128), 0, stream,
                       f, w, idxf, counts, blocksq, fin_cnt, out);
}